// Round 1
// baseline (400.251 us; speedup 1.0000x reference)
//
#include <hip/hip_runtime.h>

typedef float floatx4 __attribute__((ext_vector_type(4)));

constexpr int Bsz   = 8;
constexpr int Vsz   = 8192;
constexpr int OUTC  = 1280;
constexpr int NBINS = 3136;   // 56*56 cells on the level-3 (finest) map

// ---------------- transpose [B, C, HW] -> [B, HW, C] ----------------
// Flat 1D grid with batch in the low 3 bits: XCD round-robin dispatch puts
// batch b's tiles on XCD b. Input reads are single-use -> NT loads.
template <int C, int HW, int NTILE_HW>
__global__ __launch_bounds__(256) void transpose_kernel(const float* __restrict__ in,
                                                        float* __restrict__ out) {
    __shared__ float tile[32][33];  // +1 pad: conflict-free transpose
    const int id   = blockIdx.x;
    const int b    = id & 7;
    const int rest = id >> 3;
    const int hw0  = (rest % NTILE_HW) * 32;
    const int c0   = (rest / NTILE_HW) * 32;   // C multiple of 32
    const float* inb  = in  + (size_t)b * C * HW;
    float*       outb = out + (size_t)b * C * HW;
    const int tx = threadIdx.x & 31;
    const int ty = threadIdx.x >> 5;   // 0..7
#pragma unroll
    for (int k = 0; k < 4; ++k) {
        const int c  = c0 + ty + 8 * k;
        const int hw = hw0 + tx;                       // coalesced read along HW
        tile[ty + 8 * k][tx] =
            (hw < HW) ? __builtin_nontemporal_load(inb + (size_t)c * HW + hw) : 0.0f;
    }
    __syncthreads();
#pragma unroll
    for (int k = 0; k < 4; ++k) {
        const int hw = hw0 + ty + 8 * k;
        const int c  = c0 + tx;                        // coalesced write along C
        if (hw < HW) outb[(size_t)hw * C + c] = tile[tx][ty + 8 * k];
    }
}

// ---------------- per-batch counting sort of points by level-3 cell ----------------
// One 1024-thread block per batch. LDS histogram (3136 bins = 12.5 KB), wave-0
// chunked exclusive scan, then atomic scatter. Output record: (x, y, bitcast(v)).
// Sorted order makes the samplers' gather stream quasi-sequential: adjacent cells
// along x are adjacent 1KB/2KB rows in the transposed [HW, C] layout.
__global__ __launch_bounds__(1024) void sort_points(const float* __restrict__ coords,
                                                    float4* __restrict__ csort) {
    const int b = blockIdx.x;
    const int t = threadIdx.x;
    __shared__ unsigned hist[NBINS];
    for (int i = t; i < NBINS; i += 1024) hist[i] = 0u;
    __syncthreads();

    const float* cb = coords + (size_t)b * Vsz * 2;
    for (int i = t; i < Vsz; i += 1024) {
        const float x = cb[2 * i + 0];
        const float y = cb[2 * i + 1];
        int key = (int)floorf(y * 0.125f) * 56 + (int)floorf(x * 0.125f);
        key = min(max(key, 0), NBINS - 1);
        atomicAdd(&hist[key], 1u);
    }
    __syncthreads();

    // exclusive scan over 3136 bins: wave 0, 49 chunks of 64, shfl-based
    if (t < 64) {
        unsigned running = 0u;
        for (int c = 0; c < NBINS / 64; ++c) {
            const int idx = c * 64 + t;
            const unsigned orig = hist[idx];
            unsigned inc = orig;
#pragma unroll
            for (int off = 1; off < 64; off <<= 1) {
                const unsigned y = __shfl_up(inc, off);
                if (t >= off) inc += y;
            }
            hist[idx] = running + (inc - orig);     // exclusive offset
            running += __shfl(inc, 63);             // chunk total (broadcast)
        }
    }
    __syncthreads();

    for (int i = t; i < Vsz; i += 1024) {
        const float x = cb[2 * i + 0];
        const float y = cb[2 * i + 1];
        int key = (int)floorf(y * 0.125f) * 56 + (int)floorf(x * 0.125f);
        key = min(max(key, 0), NBINS - 1);
        const unsigned pos = atomicAdd(&hist[key], 1u);
        csort[(size_t)b * Vsz + pos] = make_float4(x, y, __int_as_float(i), 0.0f);
    }
}

// ---------------- fused sampler: all 1280 channels of one point per block-slot ----
// 320 threads = 5 waves. wave 0 -> t3 (256 ch), waves 1-2 -> t4, waves 3-4 -> t5
// (wave-uniform). Each block walks PPB consecutive SORTED points, so its gather
// rows are spatially clustered (L1 hits within block, sequential sweep in L2).
// Stores are NT full-line 5120B chunks at the point's ORIGINAL row v.
template <int PPB>
__global__ __launch_bounds__(320) void sample_fused(const float4* __restrict__ csort,
                                                    const float* __restrict__ t3,
                                                    const float* __restrict__ t4,
                                                    const float* __restrict__ t5,
                                                    float* __restrict__ out) {
    const int blk = blockIdx.x;
    const int b   = blk & 7;               // batch == XCD slot
    const int i0  = (blk >> 3) * PPB;      // sorted-point base index
    const int t   = threadIdx.x;

    const float* src; int C, W; size_t mapsz; float s;
    if (t < 64)       { src = t3; C = 256; W = 56; mapsz = (size_t)256 * 3136; s = 0.125f;   }
    else if (t < 192) { src = t4; C = 512; W = 28; mapsz = (size_t)512 * 784;  s = 0.0625f;  }
    else              { src = t5; C = 512; W = 14; mapsz = (size_t)512 * 196;  s = 0.03125f; }
    const int lc = (t < 64) ? 4 * t : ((t < 192) ? 4 * t - 256 : 4 * t - 768);
    const float* basep = src + (size_t)b * mapsz + lc;
    const int oc = 4 * t;                  // holds for all three segments
    const float4* cbase = csort + (size_t)b * Vsz + i0;
    float* outb = out + (size_t)b * Vsz * OUTC + oc;

    float4 cn = cbase[0];                  // prefetch point 0 (broadcast 16B)
#pragma unroll
    for (int p = 0; p < PPB; ++p) {
        const float4 cc = cn;
        if (p + 1 < PPB) cn = cbase[p + 1];

        const float sx = cc.x * s, sy = cc.y * s;
        const float fx1 = floorf(sx), fx2 = ceilf(sx);
        const float fy1 = floorf(sy), fy2 = ceilf(sy);
        const int xi1 = (int)fx1, xi2 = (int)fx2, yi1 = (int)fy1, yi2 = (int)fy2;
        const float wx1 = fx2 - sx, wx2 = sx - fx1;
        const float wy1 = fy2 - sy, wy2 = sy - fy1;
        const float w11 = wx1 * wy1, w12 = wx1 * wy2, w21 = wx2 * wy1, w22 = wx2 * wy2;

        const floatx4 a11 = *(const floatx4*)(basep + (size_t)(yi1 * W + xi1) * C);
        const floatx4 a12 = *(const floatx4*)(basep + (size_t)(yi2 * W + xi1) * C);
        const floatx4 a21 = *(const floatx4*)(basep + (size_t)(yi1 * W + xi2) * C);
        const floatx4 a22 = *(const floatx4*)(basep + (size_t)(yi2 * W + xi2) * C);

        const floatx4 r = a11 * w11 + a12 * w12 + a21 * w21 + a22 * w22;
        const int v = __float_as_int(cc.z);
        __builtin_nontemporal_store(r, (floatx4*)(outb + (size_t)v * OUTC));
    }
}

// ---------------- fallback: sample straight from [B, C, H, W] ----------------
__global__ __launch_bounds__(320) void sample_direct(const float* __restrict__ coords,
                                                     const float* __restrict__ fm3,
                                                     const float* __restrict__ fm4,
                                                     const float* __restrict__ fm5,
                                                     float* __restrict__ out) {
    const int blk = blockIdx.x;
    const int b = blk & 7;
    const int v = blk >> 3;
    const float x = coords[(size_t)(b * Vsz + v) * 2 + 0];
    const float y = coords[(size_t)(b * Vsz + v) * 2 + 1];

    const int t = threadIdx.x;
    const float* src; int C, W, HW, lc; float sx, sy;
    if (t < 64) {
        src = fm3; C = 256; W = 56; HW = 3136; lc = 4 * t;       sx = x * 0.125f;   sy = y * 0.125f;
    } else if (t < 192) {
        src = fm4; C = 512; W = 28; HW = 784;  lc = 4 * t - 256; sx = x * 0.0625f;  sy = y * 0.0625f;
    } else {
        src = fm5; C = 512; W = 14; HW = 196;  lc = 4 * t - 768; sx = x * 0.03125f; sy = y * 0.03125f;
    }
    const float fx1 = floorf(sx), fx2 = ceilf(sx);
    const float fy1 = floorf(sy), fy2 = ceilf(sy);
    const int xi1 = (int)fx1, xi2 = (int)fx2, yi1 = (int)fy1, yi2 = (int)fy2;
    const float wx1 = fx2 - sx, wx2 = sx - fx1;
    const float wy1 = fy2 - sy, wy2 = sy - fy1;
    const float w11 = wx1 * wy1, w12 = wx1 * wy2, w21 = wx2 * wy1, w22 = wx2 * wy2;

    const float* baseb = src + (size_t)b * C * HW;
    const int o11 = yi1 * W + xi1, o12 = yi2 * W + xi1, o21 = yi1 * W + xi2, o22 = yi2 * W + xi2;
    float4 r;
    float* rp = (float*)&r;
#pragma unroll
    for (int j = 0; j < 4; ++j) {
        const float* pc = baseb + (size_t)(lc + j) * HW;
        rp[j] = pc[o11] * w11 + pc[o12] * w12 + pc[o21] * w21 + pc[o22] * w22;
    }
    *(float4*)(out + (size_t)(b * Vsz + v) * OUTC + 4 * t) = r;
}

extern "C" void kernel_launch(void* const* d_in, const int* in_sizes, int n_in,
                              void* d_out, int out_size, void* d_ws, size_t ws_size,
                              hipStream_t stream) {
    const float* c   = (const float*)d_in[0];
    const float* fm3 = (const float*)d_in[1];
    const float* fm4 = (const float*)d_in[2];
    const float* fm5 = (const float*)d_in[3];
    float* out = (float*)d_out;

    const size_t n3 = (size_t)Bsz * 256 * 3136;
    const size_t n4 = (size_t)Bsz * 512 * 784;
    const size_t n5 = (size_t)Bsz * 512 * 196;
    const size_t need = (n3 + n4 + n5) * sizeof(float)            // transposed maps (~41.7 MB)
                      + (size_t)Bsz * Vsz * sizeof(float4);       // sorted point records (512 KB)

    if (ws_size >= need) {
        float* t3 = (float*)d_ws;
        float* t4 = t3 + n3;
        float* t5 = t4 + n4;
        float4* csort = (float4*)(t5 + n5);   // 16B-aligned: (n3+n4+n5)*4 % 16 == 0
        // NTILE_HW: 3136/32=98 exact; 784 -> 25; 196 -> 7
        transpose_kernel<256, 3136, 98><<<98 * 8 * 8,  256, 0, stream>>>(fm3, t3);
        transpose_kernel<512, 784,  25><<<25 * 16 * 8, 256, 0, stream>>>(fm4, t4);
        transpose_kernel<512, 196,  7 ><<<7 * 16 * 8,  256, 0, stream>>>(fm5, t5);
        sort_points<<<Bsz, 1024, 0, stream>>>(c, csort);
        sample_fused<16><<<Bsz * (Vsz / 16), 320, 0, stream>>>(csort, t3, t4, t5, out);
    } else {
        sample_direct<<<Bsz * Vsz, 320, 0, stream>>>(c, fm3, fm4, fm5, out);
    }
}

// Round 2
// 377.134 us; speedup vs baseline: 1.0613x; 1.0613x over previous
//
#include <hip/hip_runtime.h>

typedef float floatx4 __attribute__((ext_vector_type(4)));
typedef _Float16 halfx4 __attribute__((ext_vector_type(4)));

constexpr int Bsz  = 8;
constexpr int Vsz  = 8192;
constexpr int OUTC = 1280;

// -------- transpose + fp16 convert: [B, C, HW] f32 -> [B, HW, C] f16 --------
// Batch in low 3 bits of blockIdx: XCD round-robin puts batch b's tiles (and its
// L2-resident transposed map) on XCD b, matching the sampler's b = blk&7 mapping.
// Input reads are single-use -> NT loads. fp16 halves footprint: per-XCD sampler
// working set drops 5.2 MB -> 2.6 MB < 4 MB L2 (the round-1 lesson: capacity, not
// order, is why gathers ran at L3 rate).
template <int C, int HW, int NTILE_HW>
__global__ __launch_bounds__(256) void transpose_f16(const float* __restrict__ in,
                                                     _Float16* __restrict__ out) {
    __shared__ float tile[32][33];  // +1 pad: conflict-free transpose
    const int id   = blockIdx.x;
    const int b    = id & 7;
    const int rest = id >> 3;
    const int hw0  = (rest % NTILE_HW) * 32;
    const int c0   = (rest / NTILE_HW) * 32;   // C multiple of 32
    const float* inb   = in  + (size_t)b * C * HW;
    _Float16*    outb  = out + (size_t)b * C * HW;
    const int tx = threadIdx.x & 31;
    const int ty = threadIdx.x >> 5;   // 0..7
#pragma unroll
    for (int k = 0; k < 4; ++k) {
        const int c  = c0 + ty + 8 * k;
        const int hw = hw0 + tx;                       // coalesced read along HW
        tile[ty + 8 * k][tx] =
            (hw < HW) ? __builtin_nontemporal_load(inb + (size_t)c * HW + hw) : 0.0f;
    }
    __syncthreads();
#pragma unroll
    for (int k = 0; k < 4; ++k) {
        const int hw = hw0 + ty + 8 * k;
        const int c  = c0 + tx;                        // coalesced write along C
        if (hw < HW) outb[(size_t)hw * C + c] = (_Float16)tile[tx][ty + 8 * k];
    }
}

// -------- fused sampler: all 1280 channels of PPB points per block --------
// 320 threads = 5 waves. wave 0 -> t3 (256 ch), waves 1-2 -> t4, waves 3-4 -> t5
// (wave-uniform split). Each lane covers 4 channels: 8B half4 gather loads,
// 512B contiguous per wave per corner row. Maps are fp16 and L2-resident
// (2.6 MB/XCD incl. all three levels), so gather order no longer matters —
// no sort needed. Output stays fp32, NT full-line 5120B per point.
template <int PPB>
__global__ __launch_bounds__(320) void sample_fused_h(const float* __restrict__ coords,
                                                      const _Float16* __restrict__ t3,
                                                      const _Float16* __restrict__ t4,
                                                      const _Float16* __restrict__ t5,
                                                      float* __restrict__ out) {
    const int blk = blockIdx.x;
    const int b   = blk & 7;               // batch == XCD slot
    const int i0  = (blk >> 3) * PPB;      // point base index
    const int t   = threadIdx.x;

    const _Float16* src; int C, W; size_t mapsz; float s;
    if (t < 64)       { src = t3; C = 256; W = 56; mapsz = (size_t)256 * 3136; s = 0.125f;   }
    else if (t < 192) { src = t4; C = 512; W = 28; mapsz = (size_t)512 * 784;  s = 0.0625f;  }
    else              { src = t5; C = 512; W = 14; mapsz = (size_t)512 * 196;  s = 0.03125f; }
    const int lc = (t < 64) ? 4 * t : ((t < 192) ? 4 * t - 256 : 4 * t - 768);
    const _Float16* basep = src + (size_t)b * mapsz + lc;
    const int oc = 4 * t;                  // holds for all three segments
    const float* cb = coords + ((size_t)b * Vsz + i0) * 2;
    float* outb = out + ((size_t)b * Vsz + i0) * OUTC + oc;

#pragma unroll 4
    for (int p = 0; p < PPB; ++p) {
        const float x = cb[2 * p + 0];
        const float y = cb[2 * p + 1];
        const float sx = x * s, sy = y * s;
        const float fx1 = floorf(sx), fx2 = ceilf(sx);
        const float fy1 = floorf(sy), fy2 = ceilf(sy);
        const int xi1 = (int)fx1, xi2 = (int)fx2, yi1 = (int)fy1, yi2 = (int)fy2;
        const float wx1 = fx2 - sx, wx2 = sx - fx1;
        const float wy1 = fy2 - sy, wy2 = sy - fy1;
        const float w11 = wx1 * wy1, w12 = wx1 * wy2, w21 = wx2 * wy1, w22 = wx2 * wy2;

        const halfx4 a11 = *(const halfx4*)(basep + (size_t)(yi1 * W + xi1) * C);
        const halfx4 a12 = *(const halfx4*)(basep + (size_t)(yi2 * W + xi1) * C);
        const halfx4 a21 = *(const halfx4*)(basep + (size_t)(yi1 * W + xi2) * C);
        const halfx4 a22 = *(const halfx4*)(basep + (size_t)(yi2 * W + xi2) * C);

        floatx4 r;
#pragma unroll
        for (int j = 0; j < 4; ++j) {
            r[j] = (float)a11[j] * w11 + (float)a12[j] * w12 +
                   (float)a21[j] * w21 + (float)a22[j] * w22;
        }
        __builtin_nontemporal_store(r, (floatx4*)(outb + (size_t)p * OUTC));
    }
}

// ---------------- fallback: sample straight from [B, C, H, W] ----------------
__global__ __launch_bounds__(320) void sample_direct(const float* __restrict__ coords,
                                                     const float* __restrict__ fm3,
                                                     const float* __restrict__ fm4,
                                                     const float* __restrict__ fm5,
                                                     float* __restrict__ out) {
    const int blk = blockIdx.x;
    const int b = blk & 7;
    const int v = blk >> 3;
    const float x = coords[(size_t)(b * Vsz + v) * 2 + 0];
    const float y = coords[(size_t)(b * Vsz + v) * 2 + 1];

    const int t = threadIdx.x;
    const float* src; int C, W, HW, lc; float sx, sy;
    if (t < 64) {
        src = fm3; C = 256; W = 56; HW = 3136; lc = 4 * t;       sx = x * 0.125f;   sy = y * 0.125f;
    } else if (t < 192) {
        src = fm4; C = 512; W = 28; HW = 784;  lc = 4 * t - 256; sx = x * 0.0625f;  sy = y * 0.0625f;
    } else {
        src = fm5; C = 512; W = 14; HW = 196;  lc = 4 * t - 768; sx = x * 0.03125f; sy = y * 0.03125f;
    }
    const float fx1 = floorf(sx), fx2 = ceilf(sx);
    const float fy1 = floorf(sy), fy2 = ceilf(sy);
    const int xi1 = (int)fx1, xi2 = (int)fx2, yi1 = (int)fy1, yi2 = (int)fy2;
    const float wx1 = fx2 - sx, wx2 = sx - fx1;
    const float wy1 = fy2 - sy, wy2 = sy - fy1;
    const float w11 = wx1 * wy1, w12 = wx1 * wy2, w21 = wx2 * wy1, w22 = wx2 * wy2;

    const float* baseb = src + (size_t)b * C * HW;
    const int o11 = yi1 * W + xi1, o12 = yi2 * W + xi1, o21 = yi1 * W + xi2, o22 = yi2 * W + xi2;
    float4 r;
    float* rp = (float*)&r;
#pragma unroll
    for (int j = 0; j < 4; ++j) {
        const float* pc = baseb + (size_t)(lc + j) * HW;
        rp[j] = pc[o11] * w11 + pc[o12] * w12 + pc[o21] * w21 + pc[o22] * w22;
    }
    *(float4*)(out + (size_t)(b * Vsz + v) * OUTC + 4 * t) = r;
}

extern "C" void kernel_launch(void* const* d_in, const int* in_sizes, int n_in,
                              void* d_out, int out_size, void* d_ws, size_t ws_size,
                              hipStream_t stream) {
    const float* c   = (const float*)d_in[0];
    const float* fm3 = (const float*)d_in[1];
    const float* fm4 = (const float*)d_in[2];
    const float* fm5 = (const float*)d_in[3];
    float* out = (float*)d_out;

    const size_t n3 = (size_t)Bsz * 256 * 3136;
    const size_t n4 = (size_t)Bsz * 512 * 784;
    const size_t n5 = (size_t)Bsz * 512 * 196;
    const size_t need = (n3 + n4 + n5) * sizeof(_Float16);  // fp16 maps, ~20.9 MB

    if (ws_size >= need) {
        _Float16* t3 = (_Float16*)d_ws;
        _Float16* t4 = t3 + n3;
        _Float16* t5 = t4 + n4;
        // NTILE_HW: 3136/32=98 exact; 784 -> 25; 196 -> 7
        transpose_f16<256, 3136, 98><<<98 * 8 * 8,  256, 0, stream>>>(fm3, t3);
        transpose_f16<512, 784,  25><<<25 * 16 * 8, 256, 0, stream>>>(fm4, t4);
        transpose_f16<512, 196,  7 ><<<7 * 16 * 8,  256, 0, stream>>>(fm5, t5);
        sample_fused_h<16><<<Bsz * (Vsz / 16), 320, 0, stream>>>(c, t3, t4, t5, out);
    } else {
        sample_direct<<<Bsz * Vsz, 320, 0, stream>>>(c, fm3, fm4, fm5, out);
    }
}

// Round 3
// 376.318 us; speedup vs baseline: 1.0636x; 1.0022x over previous
//
#include <hip/hip_runtime.h>

typedef float floatx4 __attribute__((ext_vector_type(4)));
typedef _Float16 halfx4 __attribute__((ext_vector_type(4)));

constexpr int Bsz  = 8;
constexpr int Vsz  = 8192;
constexpr int NPTS = Bsz * Vsz;
constexpr int OUTC = 1280;

// map sizes in elements (fp16 transposed maps)
constexpr size_t N3 = (size_t)Bsz * 256 * 3136;
constexpr size_t N4 = (size_t)Bsz * 512 * 784;
constexpr size_t N5 = (size_t)Bsz * 512 * 196;

// prep grid partition: transpose tiles for 3 levels + descriptor blocks
constexpr int TB3 = 98 * 8 * 8;    // (3136/32) hw-tiles x (256/32) c-tiles x 8 batches
constexpr int TB4 = 25 * 16 * 8;   // ceil(784/32) x (512/32) x 8
constexpr int TB5 = 7 * 16 * 8;    // ceil(196/32) x (512/32) x 8
constexpr int DTB = NPTS / 256;    // descriptor blocks, 256 pts each
constexpr int PREP_BLOCKS = TB3 + TB4 + TB5 + DTB;

// -------- transpose body: [C, HW] f32 -> [HW, C] f16 for one 32x32 tile --------
// Batch in low 3 bits of the local tile id: XCD round-robin puts batch b's tiles
// (and its L2-resident transposed map) on XCD b, matching the sampler's b = blk&7.
template <int C, int HW, int NTILE_HW>
__device__ __forceinline__ void transpose_body(int id, const float* __restrict__ in,
                                               _Float16* __restrict__ out,
                                               float (*tile)[33]) {
    const int b    = id & 7;
    const int rest = id >> 3;
    const int hw0  = (rest % NTILE_HW) * 32;
    const int c0   = (rest / NTILE_HW) * 32;   // C multiple of 32
    const float* inb  = in  + (size_t)b * C * HW;
    _Float16*    outb = out + (size_t)b * C * HW;
    const int tx = threadIdx.x & 31;
    const int ty = threadIdx.x >> 5;   // 0..7
#pragma unroll
    for (int k = 0; k < 4; ++k) {
        const int c  = c0 + ty + 8 * k;
        const int hw = hw0 + tx;                       // coalesced read along HW
        tile[ty + 8 * k][tx] =
            (hw < HW) ? __builtin_nontemporal_load(inb + (size_t)c * HW + hw) : 0.0f;
    }
    __syncthreads();
#pragma unroll
    for (int k = 0; k < 4; ++k) {
        const int hw = hw0 + ty + 8 * k;
        const int c  = c0 + tx;                        // coalesced write along C
        if (hw < HW) outb[(size_t)hw * C + c] = (_Float16)tile[tx][ty + 8 * k];
    }
}

// one level's descriptor math: exact floor/ceil corner semantics of the reference
__device__ __forceinline__ void make_desc(float x, float y, float s, int W, int C,
                                          int4& o, float4& w) {
    const float sx = x * s, sy = y * s;
    const float fx1 = floorf(sx), fx2 = ceilf(sx);
    const float fy1 = floorf(sy), fy2 = ceilf(sy);
    const int xi1 = (int)fx1, xi2 = (int)fx2, yi1 = (int)fy1, yi2 = (int)fy2;
    const float wx1 = fx2 - sx, wx2 = sx - fx1;
    const float wy1 = fy2 - sy, wy2 = sy - fy1;
    o = make_int4((yi1 * W + xi1) * C, (yi2 * W + xi1) * C,
                  (yi1 * W + xi2) * C, (yi2 * W + xi2) * C);
    w = make_float4(wx1 * wy1, wx1 * wy2, wx2 * wy1, wx2 * wy2);
}

// -------- fused prep: all three transposes + per-point descriptors, ONE launch ----
__global__ __launch_bounds__(256) void prep_all(const float* __restrict__ fm3,
                                                const float* __restrict__ fm4,
                                                const float* __restrict__ fm5,
                                                const float* __restrict__ coords,
                                                _Float16* __restrict__ t3,
                                                _Float16* __restrict__ t4,
                                                _Float16* __restrict__ t5,
                                                int4*  __restrict__ offs,   // [3][NPTS]
                                                float4* __restrict__ wts) { // [3][NPTS]
    __shared__ float tile[32][33];
    int id = blockIdx.x;
    if (id < TB3) {
        transpose_body<256, 3136, 98>(id, fm3, t3, tile);
    } else if (id < TB3 + TB4) {
        transpose_body<512, 784, 25>(id - TB3, fm4, t4, tile);
    } else if (id < TB3 + TB4 + TB5) {
        transpose_body<512, 196, 7>(id - TB3 - TB4, fm5, t5, tile);
    } else {
        const int pt = (id - TB3 - TB4 - TB5) * 256 + threadIdx.x;  // 0..NPTS-1
        const float x = coords[(size_t)pt * 2 + 0];
        const float y = coords[(size_t)pt * 2 + 1];
        int4 o; float4 w;
        make_desc(x, y, 0.125f,   56, 256, o, w); offs[pt] = o;            wts[pt] = w;
        make_desc(x, y, 0.0625f,  28, 512, o, w); offs[NPTS + pt] = o;     wts[NPTS + pt] = w;
        make_desc(x, y, 0.03125f, 14, 512, o, w); offs[2 * NPTS + pt] = o; wts[2 * NPTS + pt] = w;
    }
}

// -------- descriptor-driven sampler: all 1280 channels of PPB points per block ----
// 320 threads = 5 waves. wave 0 -> t3 (256 ch), waves 1-2 -> t4, waves 3-4 -> t5
// (wave-uniform). Inner loop per point: 2 broadcast 16B desc loads -> 4 gather
// loads (8B/lane, 512B/wave contiguous) -> 16 FMA -> one NT 16B store/lane
// (5120B contiguous per point). No floor/ceil/int-cvt in the hot loop.
template <int PPB>
__global__ __launch_bounds__(320) void sample_desc(const int4* __restrict__ offs,
                                                   const float4* __restrict__ wts,
                                                   const _Float16* __restrict__ t3,
                                                   const _Float16* __restrict__ t4,
                                                   const _Float16* __restrict__ t5,
                                                   float* __restrict__ out) {
    const int blk = blockIdx.x;
    const int b   = blk & 7;               // batch == XCD slot
    const int i0  = (blk >> 3) * PPB;      // point base within batch
    const int t   = threadIdx.x;

    const _Float16* src; size_t mapsz; int lvl;
    if (t < 64)       { src = t3; mapsz = (size_t)256 * 3136; lvl = 0; }
    else if (t < 192) { src = t4; mapsz = (size_t)512 * 784;  lvl = 1; }
    else              { src = t5; mapsz = (size_t)512 * 196;  lvl = 2; }
    const int lc = (t < 64) ? 4 * t : ((t < 192) ? 4 * t - 256 : 4 * t - 768);
    const _Float16* basep = src + (size_t)b * mapsz + lc;

    const size_t pbase = (size_t)lvl * NPTS + (size_t)b * Vsz + i0;
    const int4*   ob = offs + pbase;
    const float4* wb = wts + pbase;
    float* outb = out + ((size_t)b * Vsz + i0) * OUTC + 4 * t;

#pragma unroll 4
    for (int p = 0; p < PPB; ++p) {
        const int4   o = ob[p];            // broadcast 16B
        const float4 w = wb[p];            // broadcast 16B

        const halfx4 a11 = *(const halfx4*)(basep + o.x);
        const halfx4 a12 = *(const halfx4*)(basep + o.y);
        const halfx4 a21 = *(const halfx4*)(basep + o.z);
        const halfx4 a22 = *(const halfx4*)(basep + o.w);

        floatx4 r;
#pragma unroll
        for (int j = 0; j < 4; ++j) {
            r[j] = (float)a11[j] * w.x + (float)a12[j] * w.y +
                   (float)a21[j] * w.z + (float)a22[j] * w.w;
        }
        __builtin_nontemporal_store(r, (floatx4*)(outb + (size_t)p * OUTC));
    }
}

// ---------------- fallback: sample straight from [B, C, H, W] ----------------
__global__ __launch_bounds__(320) void sample_direct(const float* __restrict__ coords,
                                                     const float* __restrict__ fm3,
                                                     const float* __restrict__ fm4,
                                                     const float* __restrict__ fm5,
                                                     float* __restrict__ out) {
    const int blk = blockIdx.x;
    const int b = blk & 7;
    const int v = blk >> 3;
    const float x = coords[(size_t)(b * Vsz + v) * 2 + 0];
    const float y = coords[(size_t)(b * Vsz + v) * 2 + 1];

    const int t = threadIdx.x;
    const float* src; int C, W, HW, lc; float sx, sy;
    if (t < 64) {
        src = fm3; C = 256; W = 56; HW = 3136; lc = 4 * t;       sx = x * 0.125f;   sy = y * 0.125f;
    } else if (t < 192) {
        src = fm4; C = 512; W = 28; HW = 784;  lc = 4 * t - 256; sx = x * 0.0625f;  sy = y * 0.0625f;
    } else {
        src = fm5; C = 512; W = 14; HW = 196;  lc = 4 * t - 768; sx = x * 0.03125f; sy = y * 0.03125f;
    }
    const float fx1 = floorf(sx), fx2 = ceilf(sx);
    const float fy1 = floorf(sy), fy2 = ceilf(sy);
    const int xi1 = (int)fx1, xi2 = (int)fx2, yi1 = (int)fy1, yi2 = (int)fy2;
    const float wx1 = fx2 - sx, wx2 = sx - fx1;
    const float wy1 = fy2 - sy, wy2 = sy - fy1;
    const float w11 = wx1 * wy1, w12 = wx1 * wy2, w21 = wx2 * wy1, w22 = wx2 * wy2;

    const float* baseb = src + (size_t)b * C * HW;
    const int o11 = yi1 * W + xi1, o12 = yi2 * W + xi1, o21 = yi1 * W + xi2, o22 = yi2 * W + xi2;
    float4 r;
    float* rp = (float*)&r;
#pragma unroll
    for (int j = 0; j < 4; ++j) {
        const float* pc = baseb + (size_t)(lc + j) * HW;
        rp[j] = pc[o11] * w11 + pc[o12] * w12 + pc[o21] * w21 + pc[o22] * w22;
    }
    *(float4*)(out + (size_t)(b * Vsz + v) * OUTC + 4 * t) = r;
}

extern "C" void kernel_launch(void* const* d_in, const int* in_sizes, int n_in,
                              void* d_out, int out_size, void* d_ws, size_t ws_size,
                              hipStream_t stream) {
    const float* c   = (const float*)d_in[0];
    const float* fm3 = (const float*)d_in[1];
    const float* fm4 = (const float*)d_in[2];
    const float* fm5 = (const float*)d_in[3];
    float* out = (float*)d_out;

    const size_t map_bytes  = (N3 + N4 + N5) * sizeof(_Float16);   // ~20.9 MB, %16==0
    const size_t offs_bytes = (size_t)3 * NPTS * sizeof(int4);     // 3 MB
    const size_t wts_bytes  = (size_t)3 * NPTS * sizeof(float4);   // 3 MB
    const size_t need = map_bytes + offs_bytes + wts_bytes;

    if (ws_size >= need) {
        _Float16* t3 = (_Float16*)d_ws;
        _Float16* t4 = t3 + N3;
        _Float16* t5 = t4 + N4;
        int4*   offs = (int4*)((char*)d_ws + map_bytes);
        float4* wts  = (float4*)((char*)d_ws + map_bytes + offs_bytes);

        prep_all<<<PREP_BLOCKS, 256, 0, stream>>>(fm3, fm4, fm5, c, t3, t4, t5, offs, wts);
        sample_desc<8><<<Bsz * (Vsz / 8), 320, 0, stream>>>(offs, wts, t3, t4, t5, out);
    } else {
        sample_direct<<<Bsz * Vsz, 320, 0, stream>>>(c, fm3, fm4, fm5, out);
    }
}